// Round 1
// baseline (184.929 us; speedup 1.0000x reference)
//
#include <hip/hip_runtime.h>
#include <math.h>

#define B_ 2
#define C_ 96
#define H_ 64
#define W_ 64
#define L_ 4096
#define N_ 16
#define R_ 6
#define K_ 4
#define D38 (R_ + 2*N_)   // 38

// ---------------------------------------------------------------------------
// Kernel 1: transpose x_proj weights (K, 38, C) -> (K, C, 38) so the proj
// kernel's inner d-loop reads contiguous floats (s_load_dwordx8-friendly).
// ---------------------------------------------------------------------------
__global__ __launch_bounds__(256) void transpose_w_kernel(
    const float* __restrict__ w,   // (K, D38, C)
    float* __restrict__ wt)        // (K, C, D38)
{
    int i = blockIdx.x * 256 + threadIdx.x;
    if (i < K_ * D38 * C_) {
        int k   = i / (D38 * C_);
        int rem = i % (D38 * C_);
        int dd  = rem / C_;
        int cc  = rem % C_;
        wt[((size_t)k * C_ + cc) * D38 + dd] = w[i];
    }
}

// ---------------------------------------------------------------------------
// Kernel 2: per (b,k,l) compute x_dbc (38 accumulators in registers), then
//   delta = softplus(delta_proj(x_dbc[0:6]) + bias)  -> ws_delta (B,K,C,L)
//   u     = xs gather                                 -> ws_u     (B,K,C,L)
//   B,C   = x_dbc[6:22], x_dbc[22:38]                 -> ws_B/ws_C (B,K,L,N)
// Direction gather (k): 0 row-major, 1 transposed, 2/3 = flipped 0/1.
// ---------------------------------------------------------------------------
__global__ __launch_bounds__(256) void proj_kernel(
    const float* __restrict__ x,     // (B,C,L) row-major
    const float* __restrict__ wt,    // (K,C,D38)
    const float* __restrict__ dpw,   // (K,C,R)
    const float* __restrict__ dpb,   // (K,C)
    float* __restrict__ ws_delta,    // (B,K,C,L)
    float* __restrict__ ws_u,        // (B,K,C,L)
    float* __restrict__ ws_Bm,       // (B,K,L,N)
    float* __restrict__ ws_Cm)       // (B,K,L,N)
{
    int tile = blockIdx.x;               // B*K*(L/256) blocks
    int lt = tile % (L_ / 256);
    int bk = tile / (L_ / 256);
    int k  = bk % K_;
    int b  = bk / K_;
    int l  = lt * 256 + threadIdx.x;

    // gather index into x[b,c,:] for direction k at scan position l
    int m    = (k >= 2) ? (L_ - 1 - l) : l;
    int gidx = (k & 1) ? (((m & 63) << 6) | (m >> 6)) : m;

    const float* xb = x  + (size_t)b * C_ * L_;
    const float* wk = wt + (size_t)k * C_ * D38;

    float acc[D38];
    #pragma unroll
    for (int dd = 0; dd < D38; ++dd) acc[dd] = 0.f;

    for (int c = 0; c < C_; ++c) {
        float xv = xb[(size_t)c * L_ + gidx];
        const float* wc = wk + c * D38;     // uniform -> scalar loads
        #pragma unroll
        for (int dd = 0; dd < D38; ++dd) acc[dd] = fmaf(xv, wc[dd], acc[dd]);
    }

    // store B, C in (B,K,L,N): 16 consecutive floats per thread (4x float4)
    {
        float4* bw4 = (float4*)(ws_Bm + ((size_t)bk * L_ + l) * N_);
        float4* cw4 = (float4*)(ws_Cm + ((size_t)bk * L_ + l) * N_);
        #pragma unroll
        for (int q = 0; q < 4; ++q) {
            bw4[q] = make_float4(acc[R_ + 4*q], acc[R_ + 4*q + 1],
                                 acc[R_ + 4*q + 2], acc[R_ + 4*q + 3]);
            cw4[q] = make_float4(acc[R_ + N_ + 4*q], acc[R_ + N_ + 4*q + 1],
                                 acc[R_ + N_ + 4*q + 2], acc[R_ + N_ + 4*q + 3]);
        }
    }

    // delta projection (R=6 dot) + softplus; write delta and u
    const float* dwk = dpw + (size_t)k * C_ * R_;
    const float* dbk = dpb + (size_t)k * C_;
    float* dlt = ws_delta + (size_t)bk * C_ * L_ + l;
    float* uwo = ws_u     + (size_t)bk * C_ * L_ + l;
    float xu_cache; // recompute gather per c (cheap, L2-hit)
    for (int c = 0; c < C_; ++c) {
        float s = dbk[c];
        const float* dc = dwk + c * R_;     // uniform, contiguous
        #pragma unroll
        for (int r = 0; r < R_; ++r) s = fmaf(acc[r], dc[r], s);
        // softplus = logaddexp(s, 0)
        float sp = fmaxf(s, 0.f) + log1pf(__expf(-fabsf(s)));
        dlt[(size_t)c * L_] = sp;
        xu_cache = xb[(size_t)c * L_ + gidx];
        uwo[(size_t)c * L_] = xu_cache;
    }
}

// ---------------------------------------------------------------------------
// Kernel 3: selective scan. One wave (64 lanes) per channel ch=(b,k,c).
// Lane i owns l in [i*64, i*64+64), all N=16 states.
// Pass 1: per-chunk affine composite (A,B) per state.
// Wave Hillis-Steele scan (non-commutative combine) -> exclusive prefix.
// Pass 2: apply prefix, reduce over n with C, add D*u, store to the
// direction-reassembled output position.
// ---------------------------------------------------------------------------
__global__ __launch_bounds__(64) void scan_kernel(
    const float* __restrict__ ws_delta,  // (B,K,C,L)
    const float* __restrict__ ws_u,      // (B,K,C,L)
    const float* __restrict__ ws_Bm,     // (B,K,L,N)
    const float* __restrict__ ws_Cm,     // (B,K,L,N)
    const float* __restrict__ A_log,     // (K*C, N)
    const float* __restrict__ Ds,        // (K*C)
    float* __restrict__ out)             // 4 x (B,C,L) concatenated
{
    int ch = blockIdx.x;                 // (b*K + k)*C + c
    int c  = ch % C_;
    int k  = (ch / C_) % K_;
    int b  = ch / (C_ * K_);
    int bk = b * K_ + k;
    int d  = k * C_ + c;
    int lane = threadIdx.x;

    float A[N_];
    #pragma unroll
    for (int n = 0; n < N_; ++n) A[n] = -__expf(A_log[(size_t)d * N_ + n]);

    const float* dp = ws_delta + (size_t)ch * L_;
    const float* up = ws_u     + (size_t)ch * L_;
    const float* Bp = ws_Bm    + (size_t)bk * L_ * N_;
    const float* Cp = ws_Cm    + (size_t)bk * L_ * N_;

    const int CH = L_ / 64;              // 64 elements per lane
    int l0 = lane * CH;

    // ---- pass 1: chunk composite
    float Ac[N_], Bc[N_];
    #pragma unroll
    for (int n = 0; n < N_; ++n) { Ac[n] = 1.f; Bc[n] = 0.f; }

    #pragma unroll 2
    for (int j = 0; j < CH; ++j) {
        int l = l0 + j;
        float dl = dp[l];
        float ul = up[l];
        float du = dl * ul;
        const float4* bv = (const float4*)(Bp + (size_t)l * N_);
        float4 b4[4] = { bv[0], bv[1], bv[2], bv[3] };
        const float* Bl = (const float*)b4;
        #pragma unroll
        for (int n = 0; n < N_; ++n) {
            float a = __expf(dl * A[n]);
            Bc[n] = fmaf(a, Bc[n], du * Bl[n]);
            Ac[n] *= a;
        }
    }

    // ---- wave inclusive scan of composites (earlier ∘ later)
    #pragma unroll
    for (int s = 1; s < 64; s <<= 1) {
        #pragma unroll
        for (int n = 0; n < N_; ++n) {
            float Apv = __shfl_up(Ac[n], s, 64);
            float Bpv = __shfl_up(Bc[n], s, 64);
            if (lane >= s) {
                Bc[n] = fmaf(Ac[n], Bpv, Bc[n]);  // B = Acur*Bprev + Bcur
                Ac[n] *= Apv;
            }
        }
    }

    // exclusive prefix: incoming state for this lane's chunk (h_init = 0)
    float h[N_];
    #pragma unroll
    for (int n = 0; n < N_; ++n) {
        float hb = __shfl_up(Bc[n], 1, 64);
        h[n] = (lane == 0) ? 0.f : hb;
    }

    float Dd = Ds[d];
    // output tensor selection + base: return order (y0, flip(y2), y1^T, flip(y3)^T)
    int osel = (k == 0) ? 0 : (k == 2) ? 1 : (k == 1) ? 2 : 3;
    float* ob = out + ((size_t)osel * B_ + b) * ((size_t)C_ * L_) + (size_t)c * L_;

    // ---- pass 2: apply
    #pragma unroll 2
    for (int j = 0; j < CH; ++j) {
        int l = l0 + j;
        float dl = dp[l];
        float ul = up[l];
        float du = dl * ul;
        const float4* bv = (const float4*)(Bp + (size_t)l * N_);
        const float4* cv = (const float4*)(Cp + (size_t)l * N_);
        float4 b4[4] = { bv[0], bv[1], bv[2], bv[3] };
        float4 c4[4] = { cv[0], cv[1], cv[2], cv[3] };
        const float* Bl = (const float*)b4;
        const float* Cl = (const float*)c4;
        float y = Dd * ul;
        #pragma unroll
        for (int n = 0; n < N_; ++n) {
            float a = __expf(dl * A[n]);
            h[n] = fmaf(a, h[n], du * Bl[n]);
            y = fmaf(h[n], Cl[n], y);
        }
        int idx;
        if (k == 0)      idx = l;
        else if (k == 2) idx = L_ - 1 - l;
        else { int mm = (k == 1) ? l : (L_ - 1 - l); idx = ((mm & 63) << 6) | (mm >> 6); }
        ob[idx] = y;
    }
}

// ---------------------------------------------------------------------------
extern "C" void kernel_launch(void* const* d_in, const int* in_sizes, int n_in,
                              void* d_out, int out_size, void* d_ws, size_t ws_size,
                              hipStream_t stream) {
    const float* x     = (const float*)d_in[0];
    const float* xpw   = (const float*)d_in[1];
    const float* dpw   = (const float*)d_in[2];
    const float* dpb   = (const float*)d_in[3];
    const float* A_log = (const float*)d_in[4];
    const float* Ds    = (const float*)d_in[5];
    float* out = (float*)d_out;

    float* ws = (float*)d_ws;
    const size_t duL = (size_t)B_ * K_ * C_ * L_;   // 3,145,728 floats
    const size_t bcL = (size_t)B_ * K_ * L_ * N_;   //   524,288 floats
    float* ws_delta = ws;
    float* ws_u     = ws_delta + duL;
    float* ws_Bm    = ws_u + duL;
    float* ws_Cm    = ws_Bm + bcL;
    float* ws_Wt    = ws_Cm + bcL;                  // 14,592 floats
    // total ws use: ~29.4 MB

    transpose_w_kernel<<<(K_ * D38 * C_ + 255) / 256, 256, 0, stream>>>(xpw, ws_Wt);
    proj_kernel<<<B_ * K_ * (L_ / 256), 256, 0, stream>>>(
        x, ws_Wt, dpw, dpb, ws_delta, ws_u, ws_Bm, ws_Cm);
    scan_kernel<<<B_ * K_ * C_, 64, 0, stream>>>(
        ws_delta, ws_u, ws_Bm, ws_Cm, A_log, Ds, out);
}

// Round 2
// 124.884 us; speedup vs baseline: 1.4808x; 1.4808x over previous
//
#include <hip/hip_runtime.h>
#include <math.h>

#define B_ 2
#define C_ 96
#define L_ 4096
#define N_ 16
#define R_ 6
#define K_ 4
#define D38 (R_ + 2*N_)   // 38

// ---------------------------------------------------------------------------
// Kernel 0a: transpose x_proj weights (K, 38, C) -> (K, C, 38)
// ---------------------------------------------------------------------------
__global__ __launch_bounds__(256) void transpose_w_kernel(
    const float* __restrict__ w, float* __restrict__ wt)
{
    int i = blockIdx.x * 256 + threadIdx.x;
    if (i < K_ * D38 * C_) {
        int k   = i / (D38 * C_);
        int rem = i % (D38 * C_);
        int dd  = rem / C_;
        int cc  = rem % C_;
        wt[((size_t)k * C_ + cc) * D38 + dd] = w[i];
    }
}

// ---------------------------------------------------------------------------
// Kernel 0b: per-row 64x64 transpose of x -> xT  (column-major scan order)
// xT[b,c,l] = x[b,c, ((l&63)<<6) | (l>>6)]
// ---------------------------------------------------------------------------
__global__ __launch_bounds__(256) void transpose_x_kernel(
    const float* __restrict__ x, float* __restrict__ xT)
{
    __shared__ float t[64][65];
    int bc = blockIdx.x;                       // B*C tiles
    const float* src = x  + (size_t)bc * L_;
    float*       dst = xT + (size_t)bc * L_;
    int r0  = threadIdx.x >> 6;                // 0..3
    int col = threadIdx.x & 63;
    #pragma unroll
    for (int rr = 0; rr < 16; ++rr) {
        int row = rr * 4 + r0;
        t[row][col] = src[row * 64 + col];
    }
    __syncthreads();
    #pragma unroll
    for (int rr = 0; rr < 16; ++rr) {
        int row = rr * 4 + r0;
        dst[row * 64 + col] = t[col][row];
    }
}

// ---------------------------------------------------------------------------
// Kernel 1: per (b,k,l) projection. Reads x (k even) or xT (k odd), always
// coalesced (k>=2 just reverses order). Writes delta (post-softplus) and B/C.
// ---------------------------------------------------------------------------
__global__ __launch_bounds__(256) void proj_kernel(
    const float* __restrict__ x,     // (B,C,L)
    const float* __restrict__ xT,    // (B,C,L) col-major order
    const float* __restrict__ wt,    // (K,C,D38)
    const float* __restrict__ dpw,   // (K,C,R)
    const float* __restrict__ dpb,   // (K,C)
    float* __restrict__ ws_delta,    // (B,K,C,L)
    float* __restrict__ ws_Bm,       // (B,K,L,N)
    float* __restrict__ ws_Cm)       // (B,K,L,N)
{
    int tile = blockIdx.x;               // B*K*(L/256)
    int lt = tile % (L_ / 256);
    int bk = tile / (L_ / 256);
    int k  = bk % K_;
    int b  = bk / K_;
    int l  = lt * 256 + threadIdx.x;

    int m = (k >= 2) ? (L_ - 1 - l) : l;            // coalesced (maybe reversed)
    const float* src = ((k & 1) ? xT : x) + (size_t)b * C_ * L_;
    const float* wk  = wt + (size_t)k * C_ * D38;

    float acc[D38];
    #pragma unroll
    for (int dd = 0; dd < D38; ++dd) acc[dd] = 0.f;

    #pragma unroll 2
    for (int c = 0; c < C_; ++c) {
        float xv = src[(size_t)c * L_ + m];
        const float* wc = wk + c * D38;             // lane-uniform -> scalar
        #pragma unroll
        for (int dd = 0; dd < D38; ++dd) acc[dd] = fmaf(xv, wc[dd], acc[dd]);
    }

    // B, C stores: (B,K,L,N) — each thread owns a full 64B line
    {
        float4* bw4 = (float4*)(ws_Bm + ((size_t)bk * L_ + l) * N_);
        float4* cw4 = (float4*)(ws_Cm + ((size_t)bk * L_ + l) * N_);
        #pragma unroll
        for (int q = 0; q < 4; ++q) {
            bw4[q] = make_float4(acc[R_ + 4*q], acc[R_ + 4*q + 1],
                                 acc[R_ + 4*q + 2], acc[R_ + 4*q + 3]);
            cw4[q] = make_float4(acc[R_ + N_ + 4*q], acc[R_ + N_ + 4*q + 1],
                                 acc[R_ + N_ + 4*q + 2], acc[R_ + N_ + 4*q + 3]);
        }
    }

    // delta projection + softplus (coalesced stores)
    const float* dwk = dpw + (size_t)k * C_ * R_;
    const float* dbk = dpb + (size_t)k * C_;
    float* dlt = ws_delta + (size_t)bk * C_ * L_ + l;
    for (int c = 0; c < C_; ++c) {
        float s = dbk[c];
        const float* dc = dwk + c * R_;
        #pragma unroll
        for (int r = 0; r < R_; ++r) s = fmaf(acc[r], dc[r], s);
        float sp = fmaxf(s, 0.f) + log1pf(__expf(-fabsf(s)));
        dlt[(size_t)c * L_] = sp;
    }
}

// ---------------------------------------------------------------------------
// Kernel 2: selective scan. Block = 256 threads = one channel ch=(b,k,c).
// Thread (g, q): chunk g = w*16 + i (64 l's), n-quad q (4 states).
//   - delta/u staged in LDS (coalesced loads; u comes from x/xT directly)
//   - B/C float4 reads: 4 q-lanes cover a full 64B line
//   - two-level scan: 4-step shfl over 16 chunks/wave + LDS combine (4 waves)
//   - y reduced over q via shfl_xor; transposed dirs write coalesced
// ---------------------------------------------------------------------------
#define ROWP 68   // padded LDS row stride (floats)

__global__ __launch_bounds__(256) void scan_kernel(
    const float* __restrict__ ws_delta,  // (B,K,C,L)
    const float* __restrict__ x,         // (B,C,L)
    const float* __restrict__ xT,        // (B,C,L)
    const float* __restrict__ ws_Bm,     // (B,K,L,N)
    const float* __restrict__ ws_Cm,     // (B,K,L,N)
    const float* __restrict__ A_log,     // (K*C, N)
    const float* __restrict__ Ds,        // (K*C)
    float* __restrict__ out)             // 4 x (B,C,L)
{
    __shared__ float s_d[4][16 * ROWP];
    __shared__ float s_u[4][16 * ROWP];
    __shared__ float s_wA[4][N_];
    __shared__ float s_wB[4][N_];

    int ch = blockIdx.x;                 // (b*K + k)*C + c
    int c  = ch % C_;
    int k  = (ch / C_) % K_;
    int b  = ch / (C_ * K_);
    int bk = b * K_ + k;
    int d  = k * C_ + c;

    int tid  = threadIdx.x;
    int w    = tid >> 6;                 // wave 0..3
    int lane = tid & 63;
    int i    = lane >> 2;                // chunk-in-wave 0..15
    int q    = lane & 3;                 // n-quad 0..3
    int g    = w * 16 + i;               // global chunk 0..63

    float A4[4];
    #pragma unroll
    for (int e = 0; e < 4; ++e)
        A4[e] = -__expf(A_log[(size_t)d * N_ + 4*q + e]);

    // ---- stage delta chunk (1024 floats per wave), coalesced
    {
        const float* dp = ws_delta + (size_t)ch * L_ + w * 1024;
        float* sd = s_d[w];
        #pragma unroll
        for (int it = 0; it < 4; ++it) {
            int s4 = it * 256 + lane * 4;
            float4 v = *(const float4*)(dp + s4);
            *(float4*)(sd + (s4 >> 6) * ROWP + (s4 & 63)) = v;
        }
    }
    // ---- stage u chunk from x/xT (reversed for k>=2), coalesced
    {
        const float* usrc = ((k & 1) ? xT : x) + ((size_t)b * C_ + c) * L_;
        float* su = s_u[w];
        if (k < 2) {
            #pragma unroll
            for (int it = 0; it < 4; ++it) {
                int s4 = it * 256 + lane * 4;
                float4 v = *(const float4*)(usrc + w * 1024 + s4);
                *(float4*)(su + (s4 >> 6) * ROWP + (s4 & 63)) = v;
            }
        } else {
            #pragma unroll
            for (int it = 0; it < 4; ++it) {
                int s4 = it * 256 + lane * 4;
                float4 v = *(const float4*)(usrc + (4092 - w * 1024 - s4));
                *(float4*)(su + (s4 >> 6) * ROWP + (s4 & 63)) =
                    make_float4(v.w, v.z, v.y, v.x);
            }
        }
    }

    const float* sd = s_d[w] + i * ROWP;
    const float* su = s_u[w] + i * ROWP;
    const float* Bp = ws_Bm + (size_t)bk * L_ * N_;
    const float* Cp = ws_Cm + (size_t)bk * L_ * N_;

    // ---- pass 1: chunk composite for this thread's 4 states
    float Ac[4] = {1.f, 1.f, 1.f, 1.f};
    float Bc[4] = {0.f, 0.f, 0.f, 0.f};
    #pragma unroll 4
    for (int j = 0; j < 64; ++j) {
        float dl = sd[j];
        float ul = su[j];
        float du = dl * ul;
        int l = g * 64 + j;
        float4 B4 = *(const float4*)(Bp + (size_t)l * N_ + 4*q);
        const float* Bl = (const float*)&B4;
        #pragma unroll
        for (int e = 0; e < 4; ++e) {
            float a = __expf(dl * A4[e]);
            Bc[e] = fmaf(a, Bc[e], du * Bl[e]);
            Ac[e] *= a;
        }
    }

    // ---- intra-wave scan over 16 chunks (lane stride 4)
    #pragma unroll
    for (int s = 1; s < 16; s <<= 1) {
        float pA[4], pB[4];
        #pragma unroll
        for (int e = 0; e < 4; ++e) {
            pA[e] = __shfl_up(Ac[e], 4 * s, 64);
            pB[e] = __shfl_up(Bc[e], 4 * s, 64);
        }
        if (i >= s) {
            #pragma unroll
            for (int e = 0; e < 4; ++e) {
                Bc[e] = fmaf(Ac[e], pB[e], Bc[e]);
                Ac[e] *= pA[e];
            }
        }
    }

    // ---- inter-wave combine
    if (i == 15) {
        #pragma unroll
        for (int e = 0; e < 4; ++e) {
            s_wA[w][4*q + e] = Ac[e];
            s_wB[w][4*q + e] = Bc[e];
        }
    }
    __syncthreads();

    float h[4];
    #pragma unroll
    for (int e = 0; e < 4; ++e) h[e] = 0.f;
    for (int v = 0; v < w; ++v) {        // wave-incoming state (ascending)
        #pragma unroll
        for (int e = 0; e < 4; ++e)
            h[e] = fmaf(s_wA[v][4*q + e], h[e], s_wB[v][4*q + e]);
    }
    {
        float pA[4], pB[4];
        #pragma unroll
        for (int e = 0; e < 4; ++e) {
            pA[e] = __shfl_up(Ac[e], 4, 64);
            pB[e] = __shfl_up(Bc[e], 4, 64);
        }
        if (i > 0) {
            #pragma unroll
            for (int e = 0; e < 4; ++e)
                h[e] = fmaf(pA[e], h[e], pB[e]);
        }
    }

    // ---- pass 2: apply + output
    float Dd = Ds[d];
    int osel = (k == 0) ? 0 : (k == 2) ? 1 : (k == 1) ? 2 : 3;
    float* ob = out + ((size_t)osel * B_ + b) * ((size_t)C_ * L_) + (size_t)c * L_;

    #pragma unroll 4
    for (int j = 0; j < 64; ++j) {
        float dl = sd[j];
        float ul = su[j];
        float du = dl * ul;
        int l = g * 64 + j;
        float4 B4 = *(const float4*)(Bp + (size_t)l * N_ + 4*q);
        float4 C4 = *(const float4*)(Cp + (size_t)l * N_ + 4*q);
        const float* Bl = (const float*)&B4;
        const float* Cl = (const float*)&C4;
        float y = 0.f;
        #pragma unroll
        for (int e = 0; e < 4; ++e) {
            float a = __expf(dl * A4[e]);
            h[e] = fmaf(a, h[e], du * Bl[e]);
            y = fmaf(h[e], Cl[e], y);
        }
        y += __shfl_xor(y, 1, 64);
        y += __shfl_xor(y, 2, 64);
        if (q == 0) {
            y = fmaf(Dd, ul, y);
            int idx;
            if (k == 0)      idx = l;
            else if (k == 2) idx = L_ - 1 - l;
            else if (k == 1) idx = j * 64 + g;
            else             idx = (63 - j) * 64 + (63 - g);
            ob[idx] = y;
        }
    }
}

// ---------------------------------------------------------------------------
extern "C" void kernel_launch(void* const* d_in, const int* in_sizes, int n_in,
                              void* d_out, int out_size, void* d_ws, size_t ws_size,
                              hipStream_t stream) {
    const float* x     = (const float*)d_in[0];
    const float* xpw   = (const float*)d_in[1];
    const float* dpw   = (const float*)d_in[2];
    const float* dpb   = (const float*)d_in[3];
    const float* A_log = (const float*)d_in[4];
    const float* Ds    = (const float*)d_in[5];
    float* out = (float*)d_out;

    float* ws = (float*)d_ws;
    const size_t dL  = (size_t)B_ * K_ * C_ * L_;   // 3,145,728
    const size_t bcL = (size_t)B_ * K_ * L_ * N_;   //   524,288
    const size_t xL  = (size_t)B_ * C_ * L_;        //   786,432
    float* ws_delta = ws;
    float* ws_Bm    = ws_delta + dL;
    float* ws_Cm    = ws_Bm + bcL;
    float* ws_xT    = ws_Cm + bcL;
    float* ws_Wt    = ws_xT + xL;                   // 14,592 floats
    // total ~20 MB

    transpose_w_kernel<<<(K_ * D38 * C_ + 255) / 256, 256, 0, stream>>>(xpw, ws_Wt);
    transpose_x_kernel<<<B_ * C_, 256, 0, stream>>>(x, ws_xT);
    proj_kernel<<<B_ * K_ * (L_ / 256), 256, 0, stream>>>(
        x, ws_xT, ws_Wt, dpw, dpb, ws_delta, ws_Bm, ws_Cm);
    scan_kernel<<<B_ * K_ * C_, 256, 0, stream>>>(
        ws_delta, x, ws_xT, ws_Bm, ws_Cm, A_log, Ds, out);
}

// Round 3
// 92.816 us; speedup vs baseline: 1.9924x; 1.3455x over previous
//
#include <hip/hip_runtime.h>
#include <math.h>

#define B_ 2
#define C_ 96
#define L_ 4096
#define N_ 16
#define R_ 6
#define K_ 4
#define D38 (R_ + 2*N_)   // 38

// ---------------------------------------------------------------------------
// Kernel 0a: transpose x_proj weights (K, 38, C) -> (K, C, 38)
// ---------------------------------------------------------------------------
__global__ __launch_bounds__(256) void transpose_w_kernel(
    const float* __restrict__ w, float* __restrict__ wt)
{
    int i = blockIdx.x * 256 + threadIdx.x;
    if (i < K_ * D38 * C_) {
        int k   = i / (D38 * C_);
        int rem = i % (D38 * C_);
        int dd  = rem / C_;
        int cc  = rem % C_;
        wt[((size_t)k * C_ + cc) * D38 + dd] = w[i];
    }
}

// ---------------------------------------------------------------------------
// Kernel 0b: per-row 64x64 transpose of x -> xT (column-major scan order)
// ---------------------------------------------------------------------------
__global__ __launch_bounds__(256) void transpose_x_kernel(
    const float* __restrict__ x, float* __restrict__ xT)
{
    __shared__ float t[64][65];
    int bc = blockIdx.x;
    const float* src = x  + (size_t)bc * L_;
    float*       dst = xT + (size_t)bc * L_;
    int r0  = threadIdx.x >> 6;
    int col = threadIdx.x & 63;
    #pragma unroll
    for (int rr = 0; rr < 16; ++rr) {
        int row = rr * 4 + r0;
        t[row][col] = src[row * 64 + col];
    }
    __syncthreads();
    #pragma unroll
    for (int rr = 0; rr < 16; ++rr) {
        int row = rr * 4 + r0;
        dst[row * 64 + col] = t[col][row];
    }
}

// ---------------------------------------------------------------------------
// Kernel 1: projection, 64-l tile per block, 38 outputs split over 4 wave
// groups (10 accumulators each -> no spill). LDS transpose for coalesced
// B/C float4 stores; delta-proj with wave-uniform c.
// grid = B*K*(L/64) = 512 blocks.
// ---------------------------------------------------------------------------
__global__ __launch_bounds__(256) void proj_kernel(
    const float* __restrict__ x,     // (B,C,L)
    const float* __restrict__ xT,    // (B,C,L) col-major order
    const float* __restrict__ wt,    // (K,C,D38)
    const float* __restrict__ dpw,   // (K,C,R)
    const float* __restrict__ dpb,   // (K,C)
    float* __restrict__ ws_delta,    // (B,K,C,L)
    float* __restrict__ ws_Bm,       // (B,K,L,N)
    float* __restrict__ ws_Cm)       // (B,K,L,N)
{
    __shared__ float T[64][41];      // 38 outputs per l, padded stride 41

    int tile = blockIdx.x;           // 0..511
    int lt   = tile & 63;            // l-tile
    int bk   = tile >> 6;            // 0..7
    int k    = bk & 3;
    int b    = bk >> 2;
    int tid  = threadIdx.x;
    int l0   = tid & 63;
    int dq   = tid >> 6;             // wave id 0..3
    int base = (dq == 3) ? 28 : dq * 10;   // dq3 overlaps 28,29 (benign dup)

    int l = lt * 64 + l0;
    int m = (k >= 2) ? (L_ - 1 - l) : l;
    const float* src = ((k & 1) ? xT : x) + (size_t)b * C_ * L_;
    const float* wk  = wt + (size_t)k * C_ * D38 + base;

    float acc[10];
    #pragma unroll
    for (int t = 0; t < 10; ++t) acc[t] = 0.f;

    #pragma unroll 4
    for (int c = 0; c < C_; ++c) {
        float xv = src[(size_t)c * L_ + m];
        const float* wc = wk + c * D38;
        #pragma unroll
        for (int t = 0; t < 10; ++t) acc[t] = fmaf(xv, wc[t], acc[t]);
    }

    #pragma unroll
    for (int t = 0; t < 10; ++t) T[l0][base + t] = acc[t];
    __syncthreads();

    // ---- B/C cooperative coalesced stores
    {
        int lq = tid >> 2, q = tid & 3;
        size_t o = ((size_t)bk * L_ + lt * 64 + lq) * N_ + 4 * q;
        float4 bv = make_float4(T[lq][R_ + 4*q],     T[lq][R_ + 4*q + 1],
                                T[lq][R_ + 4*q + 2], T[lq][R_ + 4*q + 3]);
        float4 cv = make_float4(T[lq][R_ + N_ + 4*q],     T[lq][R_ + N_ + 4*q + 1],
                                T[lq][R_ + N_ + 4*q + 2], T[lq][R_ + N_ + 4*q + 3]);
        *(float4*)(ws_Bm + o) = bv;
        *(float4*)(ws_Cm + o) = cv;
    }

    // ---- delta projection + softplus; c = cc*4 + dq is wave-uniform
    float ar[R_];
    #pragma unroll
    for (int r = 0; r < R_; ++r) ar[r] = T[l0][r];
    const float* dwk = dpw + (size_t)k * C_ * R_;
    const float* dbk = dpb + (size_t)k * C_;
    float* dlt = ws_delta + (size_t)bk * C_ * L_ + lt * 64 + l0;
    #pragma unroll 2
    for (int cc = 0; cc < C_ / 4; ++cc) {
        int c = cc * 4 + dq;
        float s = dbk[c];
        const float* dc = dwk + c * R_;
        #pragma unroll
        for (int r = 0; r < R_; ++r) s = fmaf(ar[r], dc[r], s);
        float sp = fmaxf(s, 0.f) + log1pf(__expf(-fabsf(s)));
        dlt[(size_t)c * L_] = sp;
    }
}

// ---------------------------------------------------------------------------
// Kernel 2: selective scan. Block = 512 threads (8 waves) per channel.
// Thread (g,q): chunk g = w*16+i owns 32 l's, n-quad q. Padded LDS rows (33)
// for conflict-free chunk reads. Two-level scan: 4-step shfl + 8-wave LDS
// combine.  grid = 768 blocks.
// ---------------------------------------------------------------------------
#define SCH 32            // l's per chunk
#define SROW 33           // padded row stride

__global__ __launch_bounds__(512) void scan_kernel(
    const float* __restrict__ ws_delta,  // (B,K,C,L)
    const float* __restrict__ x,         // (B,C,L)
    const float* __restrict__ xT,        // (B,C,L)
    const float* __restrict__ ws_Bm,     // (B,K,L,N)
    const float* __restrict__ ws_Cm,     // (B,K,L,N)
    const float* __restrict__ A_log,     // (K*C, N)
    const float* __restrict__ Ds,        // (K*C)
    float* __restrict__ out)             // 4 x (B,C,L)
{
    __shared__ float s_d[8][16 * SROW];
    __shared__ float s_u[8][16 * SROW];
    __shared__ float s_wA[8][N_];
    __shared__ float s_wB[8][N_];

    int ch = blockIdx.x;                 // (b*K + k)*C + c
    int c  = ch % C_;
    int k  = (ch / C_) % K_;
    int b  = ch / (C_ * K_);
    int bk = b * K_ + k;
    int d  = k * C_ + c;

    int tid  = threadIdx.x;
    int w    = tid >> 6;                 // wave 0..7
    int lane = tid & 63;
    int i    = lane >> 2;                // chunk-in-wave 0..15
    int q    = lane & 3;                 // n-quad
    int g    = w * 16 + i;               // global chunk 0..127

    float A4[4];
    #pragma unroll
    for (int e = 0; e < 4; ++e)
        A4[e] = -__expf(A_log[(size_t)d * N_ + 4*q + e]);

    // ---- stage delta (512 floats per wave), coalesced
    {
        const float* dp = ws_delta + (size_t)ch * L_ + w * 512;
        float* sd0 = s_d[w];
        #pragma unroll
        for (int it = 0; it < 2; ++it) {
            int e = it * 256 + lane * 4;
            float4 v = *(const float4*)(dp + e);
            *(float4*)(sd0 + (e >> 5) * SROW + (e & 31)) = v;
        }
    }
    // ---- stage u from x/xT (reversed for k>=2), coalesced
    {
        const float* usrc = ((k & 1) ? xT : x) + ((size_t)b * C_ + c) * L_;
        float* su0 = s_u[w];
        if (k < 2) {
            #pragma unroll
            for (int it = 0; it < 2; ++it) {
                int e = it * 256 + lane * 4;
                float4 v = *(const float4*)(usrc + w * 512 + e);
                *(float4*)(su0 + (e >> 5) * SROW + (e & 31)) = v;
            }
        } else {
            #pragma unroll
            for (int it = 0; it < 2; ++it) {
                int e = it * 256 + lane * 4;
                float4 v = *(const float4*)(usrc + (L_ - 4 - w * 512 - e));
                *(float4*)(su0 + (e >> 5) * SROW + (e & 31)) =
                    make_float4(v.w, v.z, v.y, v.x);
            }
        }
    }

    const float* sd = s_d[w] + i * SROW;
    const float* su = s_u[w] + i * SROW;
    const float* Bp = ws_Bm + (size_t)bk * L_ * N_;
    const float* Cp = ws_Cm + (size_t)bk * L_ * N_;

    // ---- pass 1: chunk composite
    float Ac[4] = {1.f, 1.f, 1.f, 1.f};
    float Bc[4] = {0.f, 0.f, 0.f, 0.f};
    #pragma unroll 4
    for (int j = 0; j < SCH; ++j) {
        float dl = sd[j];
        float ul = su[j];
        float du = dl * ul;
        int l = g * SCH + j;
        float4 B4 = *(const float4*)(Bp + (size_t)l * N_ + 4*q);
        const float* Bl = (const float*)&B4;
        #pragma unroll
        for (int e = 0; e < 4; ++e) {
            float a = __expf(dl * A4[e]);
            Bc[e] = fmaf(a, Bc[e], du * Bl[e]);
            Ac[e] *= a;
        }
    }

    // ---- intra-wave scan over 16 chunks
    #pragma unroll
    for (int s = 1; s < 16; s <<= 1) {
        float pA[4], pB[4];
        #pragma unroll
        for (int e = 0; e < 4; ++e) {
            pA[e] = __shfl_up(Ac[e], 4 * s, 64);
            pB[e] = __shfl_up(Bc[e], 4 * s, 64);
        }
        if (i >= s) {
            #pragma unroll
            for (int e = 0; e < 4; ++e) {
                Bc[e] = fmaf(Ac[e], pB[e], Bc[e]);
                Ac[e] *= pA[e];
            }
        }
    }

    // ---- inter-wave combine
    if (i == 15) {
        #pragma unroll
        for (int e = 0; e < 4; ++e) {
            s_wA[w][4*q + e] = Ac[e];
            s_wB[w][4*q + e] = Bc[e];
        }
    }
    __syncthreads();

    float h[4] = {0.f, 0.f, 0.f, 0.f};
    for (int v = 0; v < w; ++v) {
        #pragma unroll
        for (int e = 0; e < 4; ++e)
            h[e] = fmaf(s_wA[v][4*q + e], h[e], s_wB[v][4*q + e]);
    }
    {
        float pA[4], pB[4];
        #pragma unroll
        for (int e = 0; e < 4; ++e) {
            pA[e] = __shfl_up(Ac[e], 4, 64);
            pB[e] = __shfl_up(Bc[e], 4, 64);
        }
        if (i > 0) {
            #pragma unroll
            for (int e = 0; e < 4; ++e)
                h[e] = fmaf(pA[e], h[e], pB[e]);
        }
    }

    // ---- pass 2: apply + output
    float Dd = Ds[d];
    int osel = (k == 0) ? 0 : (k == 2) ? 1 : (k == 1) ? 2 : 3;
    float* ob = out + ((size_t)osel * B_ + b) * ((size_t)C_ * L_) + (size_t)c * L_;

    #pragma unroll 4
    for (int j = 0; j < SCH; ++j) {
        float dl = sd[j];
        float ul = su[j];
        float du = dl * ul;
        int l = g * SCH + j;
        float4 B4 = *(const float4*)(Bp + (size_t)l * N_ + 4*q);
        float4 C4 = *(const float4*)(Cp + (size_t)l * N_ + 4*q);
        const float* Bl = (const float*)&B4;
        const float* Cl = (const float*)&C4;
        float y = 0.f;
        #pragma unroll
        for (int e = 0; e < 4; ++e) {
            float a = __expf(dl * A4[e]);
            h[e] = fmaf(a, h[e], du * Bl[e]);
            y = fmaf(h[e], Cl[e], y);
        }
        y += __shfl_xor(y, 1, 64);
        y += __shfl_xor(y, 2, 64);
        if (q == 0) {
            y = fmaf(Dd, ul, y);
            int idx;
            if (k == 0)      idx = l;
            else if (k == 2) idx = L_ - 1 - l;
            else if (k == 1) idx = ((l & 63) << 6) | (l >> 6);
            else { int mm = L_ - 1 - l; idx = ((mm & 63) << 6) | (mm >> 6); }
            ob[idx] = y;
        }
    }
}

// ---------------------------------------------------------------------------
extern "C" void kernel_launch(void* const* d_in, const int* in_sizes, int n_in,
                              void* d_out, int out_size, void* d_ws, size_t ws_size,
                              hipStream_t stream) {
    const float* x     = (const float*)d_in[0];
    const float* xpw   = (const float*)d_in[1];
    const float* dpw   = (const float*)d_in[2];
    const float* dpb   = (const float*)d_in[3];
    const float* A_log = (const float*)d_in[4];
    const float* Ds    = (const float*)d_in[5];
    float* out = (float*)d_out;

    float* ws = (float*)d_ws;
    const size_t dL  = (size_t)B_ * K_ * C_ * L_;   // 3,145,728
    const size_t bcL = (size_t)B_ * K_ * L_ * N_;   //   524,288
    const size_t xL  = (size_t)B_ * C_ * L_;        //   786,432
    float* ws_delta = ws;
    float* ws_Bm    = ws_delta + dL;
    float* ws_Cm    = ws_Bm + bcL;
    float* ws_xT    = ws_Cm + bcL;
    float* ws_Wt    = ws_xT + xL;

    transpose_w_kernel<<<(K_ * D38 * C_ + 255) / 256, 256, 0, stream>>>(xpw, ws_Wt);
    transpose_x_kernel<<<B_ * C_, 256, 0, stream>>>(x, ws_xT);
    proj_kernel<<<B_ * K_ * (L_ / 64), 256, 0, stream>>>(
        x, ws_xT, ws_Wt, dpw, dpb, ws_delta, ws_Bm, ws_Cm);
    scan_kernel<<<B_ * K_ * C_, 512, 0, stream>>>(
        ws_delta, x, ws_xT, ws_Bm, ws_Cm, A_log, Ds, out);
}